// Round 9
// baseline (227.184 us; speedup 1.0000x reference)
//
#include <hip/hip_runtime.h>
#include <hip/hip_bf16.h>
#include <math.h>

// Problem constants
#define NL 4096     // L patches
#define NQ 4096     // HS*WS pixels
#define SCALE 10.0f

typedef __bf16 bf16x8 __attribute__((ext_vector_type(8)));
typedef float  f32x4  __attribute__((ext_vector_type(4)));

#define GLOAD_LDS16(gp, lp)                                                        \
    __builtin_amdgcn_global_load_lds((const __attribute__((address_space(1))) void*)(gp), \
                                     (__attribute__((address_space(3))) void*)(lp), \
                                     16, 0, 0)

// ---------------------------------------------------------------------------
// K1: fully-fused double-diagonal pass. Round-9 rewrite for ILP:
// 16 outputs/thread; each tap row = 5 ALIGNED f32x4 loads into a 20-float
// register window + compile-time-shift extraction (SH = (colb+d1)&3, fixed
// per alignment class). 9 independent rows give deep load ILP (round-8
// version was a VGPR=16 latency chain).
// ---------------------------------------------------------------------------
template <int SH>
__device__ __forceinline__ void rowAcc(const float* __restrict__ S, int row,
                                       int base, float* __restrict__ tmp) {
    if (row < 0 || row >= 4096) return;
    const float* p = S + (size_t)row * 4096;
    float r[20];
    #pragma unroll
    for (int i = 0; i < 5; ++i) {
        int c = base + i * 4;
        if (c >= 0 && c <= 4092) {
            f32x4 v = *(const f32x4*)(p + c);
            r[i * 4 + 0] = v.x; r[i * 4 + 1] = v.y;
            r[i * 4 + 2] = v.z; r[i * 4 + 3] = v.w;
        } else {
            #pragma unroll
            for (int j = 0; j < 4; ++j) {
                int cj = c + j;
                r[i * 4 + j] = (cj >= 0 && cj < 4096) ? p[cj] : 0.f;
            }
        }
    }
    #pragma unroll
    for (int j = 0; j < 16; ++j) tmp[j] += r[SH + j];
}

__global__ __launch_bounds__(256) void fuseD(const float* __restrict__ S,
                                             float* __restrict__ F) {
    int lin = blockIdx.x;
    int l = (lin & 7) * 512 + (lin >> 3);    // bijective XCD chunking (4096%8==0)
    int hb = l >> 6, wb = l & 63;
    int q0 = threadIdx.x * 16;
    int hs = q0 >> 6, ws0 = q0 & 63;         // ws0 in {0,16,32,48}

    float acc[16] = {};
    #pragma unroll
    for (int d = 0; d < 3; ++d) {
        int h2 = hb + d - 1;
        int rowb; bool rokd;
        if (h2 >= 0 && h2 <= 63) { rowb = h2 * 64 + wb; rokd = true; }
        else if (h2 < 0)         { rowb = 4031 + wb;    rokd = (wb >= 1); }
        else                     { rowb = 1 + wb;       rokd = (wb <= 62); }
        if (!rokd) continue;                  // block-uniform

        int s2 = hs + d - 1;
        float tmp[16] = {};
        if (s2 >= 0 && s2 <= 63) {            // interior: colb % 16 == 0
            int colb = s2 * 64 + ws0;
            rowAcc<3>(S, rowb - 1, colb - 4, tmp);   // cb=colb-1
            rowAcc<0>(S, rowb,     colb,     tmp);   // cb=colb
            rowAcc<1>(S, rowb + 1, colb,     tmp);   // cb=colb+1
        } else if (s2 < 0) {                  // wrapL: colb % 4 == 3
            int colb = 4031 + ws0;
            rowAcc<2>(S, rowb - 1, colb - 3, tmp);   // cb=colb-1 (==2 mod 4)
            rowAcc<3>(S, rowb,     colb - 3, tmp);   // cb=colb   (==3 mod 4)
            rowAcc<0>(S, rowb + 1, colb + 1, tmp);   // cb=colb+1 (==0 mod 4)
            if (ws0 == 0) tmp[0] = 0.f;              // ws==0 invalid for wrapL
        } else {                              // wrapR: colb % 4 == 1
            int colb = 1 + ws0;
            rowAcc<0>(S, rowb - 1, colb - 1, tmp);   // cb=colb-1 (==0 mod 4)
            rowAcc<1>(S, rowb,     colb - 1, tmp);   // cb=colb   (==1 mod 4)
            rowAcc<2>(S, rowb + 1, colb - 1, tmp);   // cb=colb+1 (==2 mod 4)
            if (ws0 == 48) tmp[15] = 0.f;            // ws==63 invalid for wrapR
        }
        #pragma unroll
        for (int j = 0; j < 16; ++j) acc[j] += tmp[j];
    }

    float* Fr = F + (size_t)l * 4096 + q0;
    #pragma unroll
    for (int i = 0; i < 4; ++i)
        *(f32x4*)&Fr[i * 4] = *(const f32x4*)&acc[i * 4];
}

// ---------------------------------------------------------------------------
// S1: partial softmax stats on F[l][q] (column softmax).
// ---------------------------------------------------------------------------
__global__ __launch_bounds__(256) void softPart(const float* __restrict__ F,
                                                const float* __restrict__ mm,
                                                float* __restrict__ Pm,
                                                float* __restrict__ Ps) {
    int qt = blockIdx.x, lc = blockIdx.y;
    int qo = threadIdx.x & 63, lg = threadIdx.x >> 6;
    int q = qt * 64 + qo;
    __shared__ float red[4][64];

    float sv[32];
    float m = -1e30f;
    #pragma unroll
    for (int i = 0; i < 32; ++i) {
        int l = lc * 128 + i * 4 + lg;
        float s = F[(size_t)l * 4096 + q] * mm[l] * SCALE;
        sv[i] = s;
        m = fmaxf(m, s);
    }
    red[lg][qo] = m;
    __syncthreads();
    m = fmaxf(fmaxf(red[0][qo], red[1][qo]), fmaxf(red[2][qo], red[3][qo]));
    __syncthreads();

    float sum = 0.f;
    #pragma unroll
    for (int i = 0; i < 32; ++i) sum += __expf(sv[i] - m);
    red[lg][qo] = sum;
    __syncthreads();
    if (lg == 0) {
        sum = red[0][qo] + red[1][qo] + red[2][qo] + red[3][qo];
        Pm[lc * 4096 + q] = m;
        Ps[lc * 4096 + q] = sum;
    }
}

// ---------------------------------------------------------------------------
// S2: combine 32 chunk partials per q.
// ---------------------------------------------------------------------------
__global__ void softComb(const float* __restrict__ Pm, const float* __restrict__ Ps,
                         float* __restrict__ Qm, float* __restrict__ Qi) {
    int q = blockIdx.x * 256 + threadIdx.x;
    float M = -1e30f;
    #pragma unroll
    for (int i = 0; i < 32; ++i) M = fmaxf(M, Pm[i * 4096 + q]);
    float S = 0.f;
    #pragma unroll
    for (int i = 0; i < 32; ++i) S += Ps[i * 4096 + q] * __expf(Pm[i * 4096 + q] - M);
    Qm[q] = M;
    Qi[q] = 1.0f / S;
}

// ---------------------------------------------------------------------------
// S3: normalize + bf16 convert + transpose. Pt[m=q][k=l] = bf16(P[l][q]).
// ---------------------------------------------------------------------------
__global__ __launch_bounds__(256) void normTransP(const float* __restrict__ F,
                                                  const float* __restrict__ mm,
                                                  const float* __restrict__ Qm,
                                                  const float* __restrict__ Qi,
                                                  __hip_bfloat16* __restrict__ Pt) {
    __shared__ float T[64][65];
    int qt = blockIdx.x, lt = blockIdx.y;
    int c = threadIdx.x & 63;
    int q = qt * 64 + c;
    float qm = Qm[q], qi = Qi[q];
    #pragma unroll
    for (int p = 0; p < 16; ++p) {
        int r = p * 4 + (threadIdx.x >> 6);
        int l = lt * 64 + r;
        float mml = mm[l];
        float s = F[(size_t)l * 4096 + q] * mml * SCALE - qm;
        T[r][c] = mml * __expf(s) * qi;
    }
    __syncthreads();
    #pragma unroll
    for (int p = 0; p < 16; ++p) {
        int r = p * 4 + (threadIdx.x >> 6);
        Pt[(size_t)(qt * 64 + r) * 4096 + lt * 64 + c] = (__hip_bfloat16)T[c][r];
    }
}

// ---------------------------------------------------------------------------
// Wt: transpose + convert raw_w [k][ck] fp32 -> Wt [n][k] bf16, with the
// GEMM N-dim permuted as n = kyx*64 + c (so scatterD reads Mo coalesced).
// ---------------------------------------------------------------------------
__global__ __launch_bounds__(256) void transW(const float* __restrict__ Wsrc,
                                              __hip_bfloat16* __restrict__ Wt) {
    __shared__ float T[64][65];
    int nt = blockIdx.x, kt = blockIdx.y;
    int c = threadIdx.x & 63;
    #pragma unroll
    for (int p = 0; p < 16; ++p) {
        int r = p * 4 + (threadIdx.x >> 6);
        T[r][c] = Wsrc[(size_t)(kt * 64 + r) * 1024 + nt * 64 + c];
    }
    __syncthreads();
    #pragma unroll
    for (int p = 0; p < 16; ++p) {
        int r = p * 4 + (threadIdx.x >> 6);   // r = ck_local; ck = nt*64 + r
        int n_new = (r & 15) * 64 + nt * 4 + (r >> 4);   // kyx*64 + c_chan
        Wt[(size_t)n_new * 4096 + kt * 64 + c] = (__hip_bfloat16)T[c][r];
    }
}

// ---------------------------------------------------------------------------
// Wc prep: conv weight [co][ci][3][3] fp32 -> Wc[kyx][co][ci] bf16.
// ---------------------------------------------------------------------------
__global__ void transWc(const float* __restrict__ Wsrc, __hip_bfloat16* __restrict__ Wd) {
    int t = blockIdx.x * 256 + threadIdx.x;   // kyx*4096 + co*64 + ci
    int kyx = t >> 12;
    int co = (t >> 6) & 63;
    int ci = t & 63;
    Wd[t] = (__hip_bfloat16)Wsrc[co * 576 + ci * 9 + kyx];
}

// ---------------------------------------------------------------------------
// K4: bf16 MFMA GEMM, K-SPLIT x2. C_z[m][n] = sum_{k in half z} Pt[m][k]*Wt[n][k].
// 128x128 tile, BK=32, 4 waves (2x2) each 64x64. Grid = 512 = 2 blocks/CU.
// XCD-chunked remap; both-sides XOR swizzle (conflicts=0, round 7).
// ---------------------------------------------------------------------------
__global__ __launch_bounds__(256) void gemmMfmaK(const __hip_bfloat16* __restrict__ Ab,
                                                 const __hip_bfloat16* __restrict__ Bb,
                                                 float* __restrict__ C0,
                                                 float* __restrict__ C1) {
    __shared__ __align__(16) __hip_bfloat16 As[2][128][32];  // 16 KiB
    __shared__ __align__(16) __hip_bfloat16 Bs[2][128][32];  // 16 KiB
    int lin = blockIdx.x;
    int wid = (lin & 7) * 64 + (lin >> 3);    // XCD chunking
    int bm = wid & 31;
    int bn = (wid >> 5) & 7;
    int bz = wid >> 8;
    int bm0 = bm * 128, bn0 = bn * 128;
    size_t kbase = (size_t)bz * 2048;
    float* Cm = bz ? C1 : C0;

    int tid = threadIdx.x;
    int lane = tid & 63, w = tid >> 6;
    int wm = (w >> 1) * 64, wn = (w & 1) * 64;

    int srow = w * 32 + (lane >> 2);
    int scol = (((lane & 3) ^ ((lane >> 3) & 3))) * 8;   // swizzled source col
    const __hip_bfloat16* ga0 = Ab + (size_t)(bm0 + srow) * 4096 + kbase + scol;
    const __hip_bfloat16* ga1 = Ab + (size_t)(bm0 + srow + 16) * 4096 + kbase + scol;
    const __hip_bfloat16* gb0 = Bb + (size_t)(bn0 + srow) * 4096 + kbase + scol;
    const __hip_bfloat16* gb1 = Bb + (size_t)(bn0 + srow + 16) * 4096 + kbase + scol;

    f32x4 acc[4][4] = {};
    int fm = lane & 15;
    int fkz = (((lane >> 4) ^ ((lane >> 1) & 3))) * 8;   // swizzled k-offset

    GLOAD_LDS16(ga0, &As[0][w * 32][0]);
    GLOAD_LDS16(ga1, &As[0][w * 32 + 16][0]);
    GLOAD_LDS16(gb0, &Bs[0][w * 32][0]);
    GLOAD_LDS16(gb1, &Bs[0][w * 32 + 16][0]);
    __syncthreads();

    int buf = 0;
    for (int t = 0; t < 64; ++t) {
        if (t + 1 < 64) {
            int k0 = (t + 1) * 32;
            GLOAD_LDS16(ga0 + k0, &As[buf ^ 1][w * 32][0]);
            GLOAD_LDS16(ga1 + k0, &As[buf ^ 1][w * 32 + 16][0]);
            GLOAD_LDS16(gb0 + k0, &Bs[buf ^ 1][w * 32][0]);
            GLOAD_LDS16(gb1 + k0, &Bs[buf ^ 1][w * 32 + 16][0]);
        }
        bf16x8 af[4], bfr[4];
        #pragma unroll
        for (int i = 0; i < 4; ++i)
            af[i] = *(const bf16x8*)&As[buf][wm + i * 16 + fm][fkz];
        #pragma unroll
        for (int j = 0; j < 4; ++j)
            bfr[j] = *(const bf16x8*)&Bs[buf][wn + j * 16 + fm][fkz];
        #pragma unroll
        for (int i = 0; i < 4; ++i)
            #pragma unroll
            for (int j = 0; j < 4; ++j)
                acc[i][j] = __builtin_amdgcn_mfma_f32_16x16x32_bf16(af[i], bfr[j], acc[i][j], 0, 0, 0);
        __syncthreads();
        buf ^= 1;
    }

    // D mapping: col = lane&15, row = (lane>>4)*4 + reg  [HW-verified]
    #pragma unroll
    for (int i = 0; i < 4; ++i) {
        #pragma unroll
        for (int j = 0; j < 4; ++j) {
            int row = bm0 + wm + i * 16 + (lane >> 4) * 4;
            int col = bn0 + wn + j * 16 + (lane & 15);
            #pragma unroll
            for (int r = 0; r < 4; ++r)
                Cm[(size_t)(row + r) * 1024 + col] = acc[i][j][r];
        }
    }
}

// ---------------------------------------------------------------------------
// K5: transposed-conv gather + /4, summing the two K-split halves ->
// padded NHWC bf16 Xp[130][130][64].
// ---------------------------------------------------------------------------
__global__ void scatterD(const float* __restrict__ Mo, const float* __restrict__ Mo2,
                         __hip_bfloat16* __restrict__ Xp) {
    int c = threadIdx.x & 63;
    int pix = blockIdx.x * 4 + (threadIdx.x >> 6);
    int ox = pix & 127, oy = pix >> 7;
    float acc = 0.f;
    #pragma unroll
    for (int ky = 0; ky < 4; ++ky) {
        int ty = oy + 1 - ky;
        if (ty & 1) continue;
        int iy = ty >> 1;
        if (iy < 0 || iy >= 64) continue;
        #pragma unroll
        for (int kx = 0; kx < 4; ++kx) {
            int txx = ox + 1 - kx;
            if (txx & 1) continue;
            int ix = txx >> 1;
            if (ix < 0 || ix >= 64) continue;
            size_t off = (size_t)(iy * 64 + ix) * 1024 + (ky * 4 + kx) * 64 + c;
            acc += Mo[off] + Mo2[off];
        }
    }
    Xp[((size_t)(oy + 1) * 130 + ox + 1) * 64 + c] = (__hip_bfloat16)(acc * 0.25f);
}

// ---------------------------------------------------------------------------
// K6/K7: 3x3 conv + bias + ELU as 9-offset implicit MFMA GEMM.
// ---------------------------------------------------------------------------
template <int MODE>
__global__ __launch_bounds__(256) void convMfma(const __hip_bfloat16* __restrict__ Xp,
                                                const __hip_bfloat16* __restrict__ Wc,
                                                const float* __restrict__ Bi,
                                                __hip_bfloat16* __restrict__ Yp,
                                                float* __restrict__ Yo) {
    int tid = threadIdx.x, lane = tid & 63, w = tid >> 6;
    int y = blockIdx.x >> 1, x0 = (blockIdx.x & 1) * 64;
    int co0 = w * 16;
    int fl = lane & 15, fh = lane >> 4;

    bf16x8 wb[3][3][2];
    #pragma unroll
    for (int ky = 0; ky < 3; ++ky)
        #pragma unroll
        for (int kx = 0; kx < 3; ++kx)
            #pragma unroll
            for (int kc = 0; kc < 2; ++kc)
                wb[ky][kx][kc] = *(const bf16x8*)&Wc[(size_t)((ky * 3 + kx) * 64 + co0 + fl) * 64 + kc * 32 + fh * 8];

    f32x4 acc[4] = {};
    #pragma unroll
    for (int ky = 0; ky < 3; ++ky) {
        #pragma unroll
        for (int kx = 0; kx < 3; ++kx) {
            const __hip_bfloat16* xrow = Xp + ((size_t)(y + ky) * 130 + x0 + kx) * 64;
            #pragma unroll
            for (int kc = 0; kc < 2; ++kc) {
                #pragma unroll
                for (int mt = 0; mt < 4; ++mt) {
                    bf16x8 af = *(const bf16x8*)&xrow[(mt * 16 + fl) * 64 + kc * 32 + fh * 8];
                    acc[mt] = __builtin_amdgcn_mfma_f32_16x16x32_bf16(af, wb[ky][kx][kc], acc[mt], 0, 0, 0);
                }
            }
        }
    }

    float bias = Bi[co0 + fl];
    #pragma unroll
    for (int mt = 0; mt < 4; ++mt) {
        int xb = x0 + mt * 16 + fh * 4;
        if (MODE == 0) {
            #pragma unroll
            for (int r = 0; r < 4; ++r) {
                float v = acc[mt][r] + bias;
                v = v > 0.f ? v : expm1f(v);
                Yp[((size_t)(y + 1) * 130 + xb + r + 1) * 64 + co0 + fl] = (__hip_bfloat16)v;
            }
        } else {
            float4 o;
            float* op = (float*)&o;
            #pragma unroll
            for (int r = 0; r < 4; ++r) {
                float v = acc[mt][r] + bias;
                op[r] = v > 0.f ? v : expm1f(v);
            }
            *(float4*)&Yo[(size_t)(co0 + fl) * 16384 + y * 128 + xb] = o;
        }
    }
}

// ---------------------------------------------------------------------------
extern "C" void kernel_launch(void* const* d_in, const int* in_sizes, int n_in,
                              void* d_out, int out_size, void* d_ws, size_t ws_size,
                              hipStream_t stream) {
    const float* raw_w  = (const float*)d_in[0];
    const float* mm     = (const float*)d_in[1];
    const float* scores = (const float*)d_in[2];
    const float* w1     = (const float*)d_in[3];
    const float* b1     = (const float*)d_in[4];
    const float* w2     = (const float*)d_in[5];
    const float* b2     = (const float*)d_in[6];
    float* out = (float*)d_out;

    char* ws = (char*)d_ws;
    // Workspace map (live ranges verified disjoint):
    //  [0,32)   Pt                  [32,40)  Wt
    //  [40,41)  Pm+Ps               [41,41.06) Qm,Qi
    //  [41.25,41.5) Wc1,Wc2         [42,58)  Mo (K-half 0)
    //  [58,60.1) Xp                 [61,63.1) Y1p
    //  [64,128) F (fp32, dead after normTransP) -> [64,80) Mo2 (K-half 1)
    __hip_bfloat16* Pt  = (__hip_bfloat16*)ws;                    // 32 MiB
    __hip_bfloat16* Wt  = (__hip_bfloat16*)(ws + (32ull << 20));  // 8 MiB
    float*          Pm  = (float*)(ws + (40ull << 20));           // 512 KiB
    float*          Ps  = (float*)(ws + (40ull << 20) + (512u << 10));
    float*          Qm  = (float*)(ws + (41ull << 20));           // 16 KiB
    float*          Qi  = (float*)(ws + (41ull << 20) + (64u << 10));
    __hip_bfloat16* Wc1 = (__hip_bfloat16*)(ws + (41ull << 20) + (256u << 10));  // 72 KiB
    __hip_bfloat16* Wc2 = (__hip_bfloat16*)(ws + (41ull << 20) + (384u << 10));  // 72 KiB
    float*          Mo  = (float*)(ws + (42ull << 20));           // 16 MiB
    __hip_bfloat16* Xp  = (__hip_bfloat16*)(ws + (58ull << 20));  // 2.07 MiB
    __hip_bfloat16* Y1p = (__hip_bfloat16*)(ws + (61ull << 20));  // 2.07 MiB
    float*          F   = (float*)(ws + (64ull << 20));           // 64 MiB
    float*          Mo2 = (float*)(ws + (64ull << 20));           // 16 MiB (aliases dead F)

    const size_t XP_BYTES = 130ull * 130 * 64 * sizeof(__hip_bfloat16);

    fuseD<<<4096, 256, 0, stream>>>(scores, F);
    transW<<<dim3(16, 64), 256, 0, stream>>>(raw_w, Wt);
    transWc<<<144, 256, 0, stream>>>(w1, Wc1);
    transWc<<<144, 256, 0, stream>>>(w2, Wc2);
    softPart<<<dim3(64, 32), 256, 0, stream>>>(F, mm, Pm, Ps);
    softComb<<<16, 256, 0, stream>>>(Pm, Ps, Qm, Qi);
    normTransP<<<dim3(64, 64), 256, 0, stream>>>(F, mm, Qm, Qi, Pt);
    gemmMfmaK<<<512, 256, 0, stream>>>(Pt, Wt, Mo, Mo2);   // F dead; Mo2 reuses it
    hipMemsetAsync(Xp, 0, XP_BYTES, stream);
    hipMemsetAsync(Y1p, 0, XP_BYTES, stream);
    scatterD<<<4096, 256, 0, stream>>>(Mo, Mo2, Xp);
    convMfma<0><<<256, 256, 0, stream>>>(Xp, Wc1, b1, Y1p, nullptr);
    convMfma<1><<<256, 256, 0, stream>>>(Y1p, Wc2, b2, nullptr, out);
}

// Round 10
// 174.024 us; speedup vs baseline: 1.3055x; 1.3055x over previous
//
#include <hip/hip_runtime.h>
#include <hip/hip_bf16.h>
#include <math.h>

// Problem constants
#define NL 4096     // L patches
#define NQ 4096     // HS*WS pixels
#define SCALE 10.0f

typedef __bf16 bf16x8 __attribute__((ext_vector_type(8)));
typedef float  f32x4  __attribute__((ext_vector_type(4)));
typedef float  f32x4u __attribute__((ext_vector_type(4), aligned(4)));  // 4B-aligned vec load

#define GLOAD_LDS16(gp, lp)                                                        \
    __builtin_amdgcn_global_load_lds((const __attribute__((address_space(1))) void*)(gp), \
                                     (__attribute__((address_space(3))) void*)(lp), \
                                     16, 0, 0)

// ---------------------------------------------------------------------------
// K1: fully-fused double-diagonal pass. Round-10: round-8's lane-contiguous
// layout (lane i -> 16B at base+i*16, coalesced 1KB/wave/tap) + ILP fix:
// all 9 taps loaded into 9 DISTINCT registers before any use, so the 9
// global loads are in flight together (round-8's VGPR=16 chain serialized;
// round-9's 16-wide layout broke coalescing).
// ---------------------------------------------------------------------------
__device__ __forceinline__ f32x4 ldtap4(const float* __restrict__ S, int r, int c0) {
    f32x4 z = {0.f, 0.f, 0.f, 0.f};
    if (r < 0 || r >= 4096) return z;
    const float* p = S + (size_t)r * 4096;
    if (c0 >= 0 && c0 <= 4092)
        return *(const f32x4u*)(p + c0);
    #pragma unroll
    for (int i = 0; i < 4; ++i) {
        int c = c0 + i;
        if (c >= 0 && c < 4096) z[i] = p[c];
    }
    return z;
}

__global__ __launch_bounds__(256) void fuseD(const float* __restrict__ S,
                                             float* __restrict__ F) {
    int lin = blockIdx.x;
    int l = (lin & 7) * 512 + (lin >> 3);    // bijective XCD chunking (4096%8==0)
    int hb = l >> 6, wb = l & 63;
    int rowb[3]; bool rok[3];
    #pragma unroll
    for (int d = 0; d < 3; ++d) {
        int h2 = hb + d - 1;
        if (h2 >= 0 && h2 <= 63) { rowb[d] = h2 * 64 + wb; rok[d] = true; }
        else if (h2 < 0)         { rowb[d] = 4031 + wb;    rok[d] = (wb >= 1); }
        else                     { rowb[d] = 1 + wb;       rok[d] = (wb <= 62); }
    }
    float* Fr = F + (size_t)l * 4096;

    #pragma unroll
    for (int cc = 0; cc < 4; ++cc) {
        int q0 = (cc * 256 + threadIdx.x) * 4;
        int hs = q0 >> 6, ws0 = q0 & 63;

        int colb[3]; float me0[3], me3[3];
        #pragma unroll
        for (int d = 0; d < 3; ++d) {
            int s2 = hs + d - 1;
            me0[d] = 1.f; me3[d] = 1.f;
            if (s2 >= 0 && s2 <= 63) colb[d] = s2 * 64 + ws0;
            else if (s2 < 0) { colb[d] = 4031 + ws0; if (ws0 == 0)  me0[d] = 0.f; }
            else             { colb[d] = 1 + ws0;    if (ws0 == 60) me3[d] = 0.f; }
        }

        // Issue all 9 loads into distinct registers (no use until summation).
        f32x4 z = {0.f, 0.f, 0.f, 0.f};
        f32x4 t00 = z, t01 = z, t02 = z;
        f32x4 t10 = z, t11 = z, t12 = z;
        f32x4 t20 = z, t21 = z, t22 = z;
        if (rok[0]) {
            t00 = ldtap4(S, rowb[0] - 1, colb[0] - 1);
            t01 = ldtap4(S, rowb[0],     colb[0]);
            t02 = ldtap4(S, rowb[0] + 1, colb[0] + 1);
        }
        if (rok[1]) {
            t10 = ldtap4(S, rowb[1] - 1, colb[1] - 1);
            t11 = ldtap4(S, rowb[1],     colb[1]);
            t12 = ldtap4(S, rowb[1] + 1, colb[1] + 1);
        }
        if (rok[2]) {
            t20 = ldtap4(S, rowb[2] - 1, colb[2] - 1);
            t21 = ldtap4(S, rowb[2],     colb[2]);
            t22 = ldtap4(S, rowb[2] + 1, colb[2] + 1);
        }

        f32x4 s0 = t00 + t01 + t02;
        f32x4 s1 = t10 + t11 + t12;
        f32x4 s2v = t20 + t21 + t22;
        s0[0] *= me0[0]; s0[3] *= me3[0];
        s1[0] *= me0[1]; s1[3] *= me3[1];
        s2v[0] *= me0[2]; s2v[3] *= me3[2];
        f32x4 acc = s0 + s1 + s2v;
        *(f32x4*)&Fr[q0] = acc;
    }
}

// ---------------------------------------------------------------------------
// S1: partial softmax stats on F[l][q] (column softmax).
// ---------------------------------------------------------------------------
__global__ __launch_bounds__(256) void softPart(const float* __restrict__ F,
                                                const float* __restrict__ mm,
                                                float* __restrict__ Pm,
                                                float* __restrict__ Ps) {
    int qt = blockIdx.x, lc = blockIdx.y;
    int qo = threadIdx.x & 63, lg = threadIdx.x >> 6;
    int q = qt * 64 + qo;
    __shared__ float red[4][64];

    float sv[32];
    float m = -1e30f;
    #pragma unroll
    for (int i = 0; i < 32; ++i) {
        int l = lc * 128 + i * 4 + lg;
        float s = F[(size_t)l * 4096 + q] * mm[l] * SCALE;
        sv[i] = s;
        m = fmaxf(m, s);
    }
    red[lg][qo] = m;
    __syncthreads();
    m = fmaxf(fmaxf(red[0][qo], red[1][qo]), fmaxf(red[2][qo], red[3][qo]));
    __syncthreads();

    float sum = 0.f;
    #pragma unroll
    for (int i = 0; i < 32; ++i) sum += __expf(sv[i] - m);
    red[lg][qo] = sum;
    __syncthreads();
    if (lg == 0) {
        sum = red[0][qo] + red[1][qo] + red[2][qo] + red[3][qo];
        Pm[lc * 4096 + q] = m;
        Ps[lc * 4096 + q] = sum;
    }
}

// ---------------------------------------------------------------------------
// S2: combine 32 chunk partials per q.
// ---------------------------------------------------------------------------
__global__ void softComb(const float* __restrict__ Pm, const float* __restrict__ Ps,
                         float* __restrict__ Qm, float* __restrict__ Qi) {
    int q = blockIdx.x * 256 + threadIdx.x;
    float M = -1e30f;
    #pragma unroll
    for (int i = 0; i < 32; ++i) M = fmaxf(M, Pm[i * 4096 + q]);
    float S = 0.f;
    #pragma unroll
    for (int i = 0; i < 32; ++i) S += Ps[i * 4096 + q] * __expf(Pm[i * 4096 + q] - M);
    Qm[q] = M;
    Qi[q] = 1.0f / S;
}

// ---------------------------------------------------------------------------
// S3: normalize + bf16 convert + transpose. Pt[m=q][k=l] = bf16(P[l][q]).
// ---------------------------------------------------------------------------
__global__ __launch_bounds__(256) void normTransP(const float* __restrict__ F,
                                                  const float* __restrict__ mm,
                                                  const float* __restrict__ Qm,
                                                  const float* __restrict__ Qi,
                                                  __hip_bfloat16* __restrict__ Pt) {
    __shared__ float T[64][65];
    int qt = blockIdx.x, lt = blockIdx.y;
    int c = threadIdx.x & 63;
    int q = qt * 64 + c;
    float qm = Qm[q], qi = Qi[q];
    #pragma unroll
    for (int p = 0; p < 16; ++p) {
        int r = p * 4 + (threadIdx.x >> 6);
        int l = lt * 64 + r;
        float mml = mm[l];
        float s = F[(size_t)l * 4096 + q] * mml * SCALE - qm;
        T[r][c] = mml * __expf(s) * qi;
    }
    __syncthreads();
    #pragma unroll
    for (int p = 0; p < 16; ++p) {
        int r = p * 4 + (threadIdx.x >> 6);
        Pt[(size_t)(qt * 64 + r) * 4096 + lt * 64 + c] = (__hip_bfloat16)T[c][r];
    }
}

// ---------------------------------------------------------------------------
// Wt: transpose + convert raw_w [k][ck] fp32 -> Wt [n][k] bf16, with the
// GEMM N-dim permuted as n = kyx*64 + c (so scatterD reads Mo coalesced).
// ---------------------------------------------------------------------------
__global__ __launch_bounds__(256) void transW(const float* __restrict__ Wsrc,
                                              __hip_bfloat16* __restrict__ Wt) {
    __shared__ float T[64][65];
    int nt = blockIdx.x, kt = blockIdx.y;
    int c = threadIdx.x & 63;
    #pragma unroll
    for (int p = 0; p < 16; ++p) {
        int r = p * 4 + (threadIdx.x >> 6);
        T[r][c] = Wsrc[(size_t)(kt * 64 + r) * 1024 + nt * 64 + c];
    }
    __syncthreads();
    #pragma unroll
    for (int p = 0; p < 16; ++p) {
        int r = p * 4 + (threadIdx.x >> 6);   // r = ck_local; ck = nt*64 + r
        int n_new = (r & 15) * 64 + nt * 4 + (r >> 4);   // kyx*64 + c_chan
        Wt[(size_t)n_new * 4096 + kt * 64 + c] = (__hip_bfloat16)T[c][r];
    }
}

// ---------------------------------------------------------------------------
// Wc prep: conv weight [co][ci][3][3] fp32 -> Wc[kyx][co][ci] bf16.
// ---------------------------------------------------------------------------
__global__ void transWc(const float* __restrict__ Wsrc, __hip_bfloat16* __restrict__ Wd) {
    int t = blockIdx.x * 256 + threadIdx.x;   // kyx*4096 + co*64 + ci
    int kyx = t >> 12;
    int co = (t >> 6) & 63;
    int ci = t & 63;
    Wd[t] = (__hip_bfloat16)Wsrc[co * 576 + ci * 9 + kyx];
}

// ---------------------------------------------------------------------------
// K4: bf16 MFMA GEMM, K-SPLIT x2. 128x128 tile, BK=32, 4 waves (2x2).
// Grid = 512 = 2 blocks/CU. XCD-chunked remap; both-sides XOR swizzle.
// ---------------------------------------------------------------------------
__global__ __launch_bounds__(256) void gemmMfmaK(const __hip_bfloat16* __restrict__ Ab,
                                                 const __hip_bfloat16* __restrict__ Bb,
                                                 float* __restrict__ C0,
                                                 float* __restrict__ C1) {
    __shared__ __align__(16) __hip_bfloat16 As[2][128][32];  // 16 KiB
    __shared__ __align__(16) __hip_bfloat16 Bs[2][128][32];  // 16 KiB
    int lin = blockIdx.x;
    int wid = (lin & 7) * 64 + (lin >> 3);    // XCD chunking
    int bm = wid & 31;
    int bn = (wid >> 5) & 7;
    int bz = wid >> 8;
    int bm0 = bm * 128, bn0 = bn * 128;
    size_t kbase = (size_t)bz * 2048;
    float* Cm = bz ? C1 : C0;

    int tid = threadIdx.x;
    int lane = tid & 63, w = tid >> 6;
    int wm = (w >> 1) * 64, wn = (w & 1) * 64;

    int srow = w * 32 + (lane >> 2);
    int scol = (((lane & 3) ^ ((lane >> 3) & 3))) * 8;   // swizzled source col
    const __hip_bfloat16* ga0 = Ab + (size_t)(bm0 + srow) * 4096 + kbase + scol;
    const __hip_bfloat16* ga1 = Ab + (size_t)(bm0 + srow + 16) * 4096 + kbase + scol;
    const __hip_bfloat16* gb0 = Bb + (size_t)(bn0 + srow) * 4096 + kbase + scol;
    const __hip_bfloat16* gb1 = Bb + (size_t)(bn0 + srow + 16) * 4096 + kbase + scol;

    f32x4 acc[4][4] = {};
    int fm = lane & 15;
    int fkz = (((lane >> 4) ^ ((lane >> 1) & 3))) * 8;   // swizzled k-offset

    GLOAD_LDS16(ga0, &As[0][w * 32][0]);
    GLOAD_LDS16(ga1, &As[0][w * 32 + 16][0]);
    GLOAD_LDS16(gb0, &Bs[0][w * 32][0]);
    GLOAD_LDS16(gb1, &Bs[0][w * 32 + 16][0]);
    __syncthreads();

    int buf = 0;
    for (int t = 0; t < 64; ++t) {
        if (t + 1 < 64) {
            int k0 = (t + 1) * 32;
            GLOAD_LDS16(ga0 + k0, &As[buf ^ 1][w * 32][0]);
            GLOAD_LDS16(ga1 + k0, &As[buf ^ 1][w * 32 + 16][0]);
            GLOAD_LDS16(gb0 + k0, &Bs[buf ^ 1][w * 32][0]);
            GLOAD_LDS16(gb1 + k0, &Bs[buf ^ 1][w * 32 + 16][0]);
        }
        bf16x8 af[4], bfr[4];
        #pragma unroll
        for (int i = 0; i < 4; ++i)
            af[i] = *(const bf16x8*)&As[buf][wm + i * 16 + fm][fkz];
        #pragma unroll
        for (int j = 0; j < 4; ++j)
            bfr[j] = *(const bf16x8*)&Bs[buf][wn + j * 16 + fm][fkz];
        #pragma unroll
        for (int i = 0; i < 4; ++i)
            #pragma unroll
            for (int j = 0; j < 4; ++j)
                acc[i][j] = __builtin_amdgcn_mfma_f32_16x16x32_bf16(af[i], bfr[j], acc[i][j], 0, 0, 0);
        __syncthreads();
        buf ^= 1;
    }

    // D mapping: col = lane&15, row = (lane>>4)*4 + reg  [HW-verified]
    #pragma unroll
    for (int i = 0; i < 4; ++i) {
        #pragma unroll
        for (int j = 0; j < 4; ++j) {
            int row = bm0 + wm + i * 16 + (lane >> 4) * 4;
            int col = bn0 + wn + j * 16 + (lane & 15);
            #pragma unroll
            for (int r = 0; r < 4; ++r)
                Cm[(size_t)(row + r) * 1024 + col] = acc[i][j][r];
        }
    }
}

// ---------------------------------------------------------------------------
// K5: transposed-conv gather + /4, summing the two K-split halves ->
// padded NHWC bf16 Xp[130][130][64].
// ---------------------------------------------------------------------------
__global__ void scatterD(const float* __restrict__ Mo, const float* __restrict__ Mo2,
                         __hip_bfloat16* __restrict__ Xp) {
    int c = threadIdx.x & 63;
    int pix = blockIdx.x * 4 + (threadIdx.x >> 6);
    int ox = pix & 127, oy = pix >> 7;
    float acc = 0.f;
    #pragma unroll
    for (int ky = 0; ky < 4; ++ky) {
        int ty = oy + 1 - ky;
        if (ty & 1) continue;
        int iy = ty >> 1;
        if (iy < 0 || iy >= 64) continue;
        #pragma unroll
        for (int kx = 0; kx < 4; ++kx) {
            int txx = ox + 1 - kx;
            if (txx & 1) continue;
            int ix = txx >> 1;
            if (ix < 0 || ix >= 64) continue;
            size_t off = (size_t)(iy * 64 + ix) * 1024 + (ky * 4 + kx) * 64 + c;
            acc += Mo[off] + Mo2[off];
        }
    }
    Xp[((size_t)(oy + 1) * 130 + ox + 1) * 64 + c] = (__hip_bfloat16)(acc * 0.25f);
}

// ---------------------------------------------------------------------------
// K6/K7: 3x3 conv + bias + ELU as 9-offset implicit MFMA GEMM.
// ---------------------------------------------------------------------------
template <int MODE>
__global__ __launch_bounds__(256) void convMfma(const __hip_bfloat16* __restrict__ Xp,
                                                const __hip_bfloat16* __restrict__ Wc,
                                                const float* __restrict__ Bi,
                                                __hip_bfloat16* __restrict__ Yp,
                                                float* __restrict__ Yo) {
    int tid = threadIdx.x, lane = tid & 63, w = tid >> 6;
    int y = blockIdx.x >> 1, x0 = (blockIdx.x & 1) * 64;
    int co0 = w * 16;
    int fl = lane & 15, fh = lane >> 4;

    bf16x8 wb[3][3][2];
    #pragma unroll
    for (int ky = 0; ky < 3; ++ky)
        #pragma unroll
        for (int kx = 0; kx < 3; ++kx)
            #pragma unroll
            for (int kc = 0; kc < 2; ++kc)
                wb[ky][kx][kc] = *(const bf16x8*)&Wc[(size_t)((ky * 3 + kx) * 64 + co0 + fl) * 64 + kc * 32 + fh * 8];

    f32x4 acc[4] = {};
    #pragma unroll
    for (int ky = 0; ky < 3; ++ky) {
        #pragma unroll
        for (int kx = 0; kx < 3; ++kx) {
            const __hip_bfloat16* xrow = Xp + ((size_t)(y + ky) * 130 + x0 + kx) * 64;
            #pragma unroll
            for (int kc = 0; kc < 2; ++kc) {
                #pragma unroll
                for (int mt = 0; mt < 4; ++mt) {
                    bf16x8 af = *(const bf16x8*)&xrow[(mt * 16 + fl) * 64 + kc * 32 + fh * 8];
                    acc[mt] = __builtin_amdgcn_mfma_f32_16x16x32_bf16(af, wb[ky][kx][kc], acc[mt], 0, 0, 0);
                }
            }
        }
    }

    float bias = Bi[co0 + fl];
    #pragma unroll
    for (int mt = 0; mt < 4; ++mt) {
        int xb = x0 + mt * 16 + fh * 4;
        if (MODE == 0) {
            #pragma unroll
            for (int r = 0; r < 4; ++r) {
                float v = acc[mt][r] + bias;
                v = v > 0.f ? v : expm1f(v);
                Yp[((size_t)(y + 1) * 130 + xb + r + 1) * 64 + co0 + fl] = (__hip_bfloat16)v;
            }
        } else {
            float4 o;
            float* op = (float*)&o;
            #pragma unroll
            for (int r = 0; r < 4; ++r) {
                float v = acc[mt][r] + bias;
                op[r] = v > 0.f ? v : expm1f(v);
            }
            *(float4*)&Yo[(size_t)(co0 + fl) * 16384 + y * 128 + xb] = o;
        }
    }
}

// ---------------------------------------------------------------------------
extern "C" void kernel_launch(void* const* d_in, const int* in_sizes, int n_in,
                              void* d_out, int out_size, void* d_ws, size_t ws_size,
                              hipStream_t stream) {
    const float* raw_w  = (const float*)d_in[0];
    const float* mm     = (const float*)d_in[1];
    const float* scores = (const float*)d_in[2];
    const float* w1     = (const float*)d_in[3];
    const float* b1     = (const float*)d_in[4];
    const float* w2     = (const float*)d_in[5];
    const float* b2     = (const float*)d_in[6];
    float* out = (float*)d_out;

    char* ws = (char*)d_ws;
    // Workspace map (live ranges verified disjoint):
    //  [0,32)   Pt                  [32,40)  Wt
    //  [40,41)  Pm+Ps               [41,41.06) Qm,Qi
    //  [41.25,41.5) Wc1,Wc2         [42,58)  Mo (K-half 0)
    //  [58,60.1) Xp                 [61,63.1) Y1p
    //  [64,128) F (fp32, dead after normTransP) -> [64,80) Mo2 (K-half 1)
    __hip_bfloat16* Pt  = (__hip_bfloat16*)ws;                    // 32 MiB
    __hip_bfloat16* Wt  = (__hip_bfloat16*)(ws + (32ull << 20));  // 8 MiB
    float*          Pm  = (float*)(ws + (40ull << 20));           // 512 KiB
    float*          Ps  = (float*)(ws + (40ull << 20) + (512u << 10));
    float*          Qm  = (float*)(ws + (41ull << 20));           // 16 KiB
    float*          Qi  = (float*)(ws + (41ull << 20) + (64u << 10));
    __hip_bfloat16* Wc1 = (__hip_bfloat16*)(ws + (41ull << 20) + (256u << 10));  // 72 KiB
    __hip_bfloat16* Wc2 = (__hip_bfloat16*)(ws + (41ull << 20) + (384u << 10));  // 72 KiB
    float*          Mo  = (float*)(ws + (42ull << 20));           // 16 MiB
    __hip_bfloat16* Xp  = (__hip_bfloat16*)(ws + (58ull << 20));  // 2.07 MiB
    __hip_bfloat16* Y1p = (__hip_bfloat16*)(ws + (61ull << 20));  // 2.07 MiB
    float*          F   = (float*)(ws + (64ull << 20));           // 64 MiB
    float*          Mo2 = (float*)(ws + (64ull << 20));           // 16 MiB (aliases dead F)

    const size_t XP_BYTES = 130ull * 130 * 64 * sizeof(__hip_bfloat16);

    fuseD<<<4096, 256, 0, stream>>>(scores, F);
    transW<<<dim3(16, 64), 256, 0, stream>>>(raw_w, Wt);
    transWc<<<144, 256, 0, stream>>>(w1, Wc1);
    transWc<<<144, 256, 0, stream>>>(w2, Wc2);
    softPart<<<dim3(64, 32), 256, 0, stream>>>(F, mm, Pm, Ps);
    softComb<<<16, 256, 0, stream>>>(Pm, Ps, Qm, Qi);
    normTransP<<<dim3(64, 64), 256, 0, stream>>>(F, mm, Qm, Qi, Pt);
    gemmMfmaK<<<512, 256, 0, stream>>>(Pt, Wt, Mo, Mo2);   // F dead; Mo2 reuses it
    hipMemsetAsync(Xp, 0, XP_BYTES, stream);
    hipMemsetAsync(Y1p, 0, XP_BYTES, stream);
    scatterD<<<4096, 256, 0, stream>>>(Mo, Mo2, Xp);
    convMfma<0><<<256, 256, 0, stream>>>(Xp, Wc1, b1, Y1p, nullptr);
    convMfma<1><<<256, 256, 0, stream>>>(Y1p, Wc2, b2, nullptr, out);
}